// Round 7
// baseline (1248.334 us; speedup 1.0000x reference)
//
#include <hip/hip_runtime.h>
#include <hip/hip_bf16.h>
#include <hip/hip_fp16.h>
#include <math.h>

#define L 64
#define FIXS 1048576.0f   // 2^20 fixed-point scale for attr histogram
#define WAITCNT_LGKM0 0xC07F   // vmcnt=63, expcnt=7, lgkmcnt=0

// ---------- preprocessing ----------

// one fire-and-forget 64-bit atomic per edge: (cnt<<32) | fixedpoint(attr)
__global__ void k_hist(const int* __restrict__ col, const float* __restrict__ attr,
                       unsigned long long* __restrict__ degcnt, int E) {
    int e = blockIdx.x * blockDim.x + threadIdx.x;
    if (e < E) {
        int c = col[e];
        unsigned int fx = (unsigned int)(int)rintf(attr[e] * FIXS);
        atomicAdd(&degcnt[c], (1ULL << 32) | (unsigned long long)fx);
    }
}

__global__ void k_dinv(const unsigned long long* __restrict__ degcnt,
                       float* __restrict__ dinv, int* __restrict__ cntI,
                       float* __restrict__ rcnt, int N) {
    int n = blockIdx.x * blockDim.x + threadIdx.x;
    if (n < N) {
        unsigned long long p = degcnt[n];
        int cnt = (int)(p >> 32);
        float d = (float)(unsigned int)(p & 0xffffffffULL) * (1.0f / FIXS);
        dinv[n] = (d > 0.f) ? (1.0f / sqrtf(fmaxf(d, 1e-30f))) : 0.f;
        cntI[n] = cnt;
        int c = cnt; if (c < 1) c = 1;
        rcnt[n] = 1.0f / (float)c;
    }
}

// ---------- device-wide exclusive scan of cntI -> ptr (3 small kernels) ----------

__global__ __launch_bounds__(256) void k_scan_a(const int* __restrict__ cntI,
                                                int* __restrict__ blockSums, int N) {
    __shared__ int red[4];
    int b = blockIdx.x, t = threadIdx.x;
    int base = b * 1024 + t * 4;
    int s = 0;
    #pragma unroll
    for (int i = 0; i < 4; ++i) { int idx = base + i; if (idx < N) s += cntI[idx]; }
    #pragma unroll
    for (int off = 32; off > 0; off >>= 1) s += __shfl_down(s, off);
    if ((t & 63) == 0) red[t >> 6] = s;
    __syncthreads();
    if (t == 0) blockSums[b] = red[0] + red[1] + red[2] + red[3];
}

__global__ __launch_bounds__(1024) void k_scan_b(int* __restrict__ blockSums, int B,
                                                 int* __restrict__ ptr, int N) {
    __shared__ int sh[1024];
    int t = threadIdx.x;
    sh[t] = (t < B) ? blockSums[t] : 0;
    __syncthreads();
    for (int off = 1; off < 1024; off <<= 1) {
        int v = (t >= off) ? sh[t - off] : 0;
        __syncthreads();
        sh[t] += v;
        __syncthreads();
    }
    if (t < B) blockSums[t] = (t == 0) ? 0 : sh[t - 1];   // exclusive
    if (t == B - 1) ptr[N] = sh[t];                        // total
}

__global__ __launch_bounds__(256) void k_scan_c(const int* __restrict__ cntI,
                                                const int* __restrict__ blockSums,
                                                int* __restrict__ ptr, int N) {
    __shared__ int th[256];
    int b = blockIdx.x, t = threadIdx.x;
    int base = b * 1024 + t * 4;
    int v[4]; int s = 0;
    #pragma unroll
    for (int i = 0; i < 4; ++i) {
        int idx = base + i;
        v[i] = (idx < N) ? cntI[idx] : 0;
        s += v[i];
    }
    th[t] = s;
    __syncthreads();
    for (int off = 1; off < 256; off <<= 1) {
        int x = (t >= off) ? th[t - off] : 0;
        __syncthreads();
        th[t] += x;
        __syncthreads();
    }
    int pre = ((t == 0) ? 0 : th[t - 1]) + blockSums[b];
    #pragma unroll
    for (int i = 0; i < 4; ++i) {
        int idx = base + i;
        if (idx < N) ptr[idx] = pre;
        pre += v[i];
    }
}

// ---------- binned CSR build (2 passes, streaming-friendly writes) ----------
// Pass B: append 16B records {row, norm_bits, eid, col} into the bucket's
// contiguous region (bucket = col>>7, base = colptr[col & ~127]).
__global__ void k_binB(const int* __restrict__ row, const int* __restrict__ col,
                       const float* __restrict__ attr, const float* __restrict__ dinv,
                       const int* __restrict__ colptr, int* __restrict__ bukCur,
                       int4* __restrict__ rec, int E) {
    int e = blockIdx.x * blockDim.x + threadIdx.x;
    if (e < E) {
        int r = row[e], c = col[e];
        float nrm = dinv[r] * attr[e] * dinv[c];
        int b = c >> 7;
        int p = colptr[c & ~127] + atomicAdd(&bukCur[b], 1);
        rec[p] = make_int4(r, __float_as_int(nrm), e, c);
    }
}

// Pass C: one block per bucket; LDS per-col cursors; final scatter stays
// inside the bucket's ~16-32KB window (lines fully dirtied -> no amplification).
__global__ __launch_bounds__(256) void k_binC(const int4* __restrict__ rec,
                                              const int* __restrict__ colptr,
                                              int2* __restrict__ csrRW,
                                              int* __restrict__ csrE, int N) {
    __shared__ int cur[128];
    int b = blockIdx.x;
    int c0 = b << 7;
    int c1 = c0 + 128; if (c1 > N) c1 = N;
    int start = colptr[c0], end = colptr[c1];
    if (threadIdx.x < 128) cur[threadIdx.x] = 0;
    __syncthreads();
    for (int i = start + threadIdx.x; i < end; i += 256) {
        int4 r = rec[i];
        int rank = atomicAdd(&cur[r.w - c0], 1);
        int pos = colptr[r.w] + rank;
        csrRW[pos] = make_int2(r.x, r.y);
        csrE[pos] = r.z;
    }
}

// ---------- encoder (fp16 h) ----------

__global__ void k_encode(const float* __restrict__ x, const float* __restrict__ w_enc,
                         const float* __restrict__ b_enc, __half* __restrict__ h, int N) {
    int idx = blockIdx.x * blockDim.x + threadIdx.x;
    if (idx < N * L) {
        int n = idx >> 6, f = idx & 63;
        h[idx] = __float2half(x[n] * w_enc[f] + b_enc[f]);
    }
}

// ---------- fused GCN layer (fp16 h storage, fp32 accumulate) ----------

__global__ __launch_bounds__(256) void k_gcn(const uint2* __restrict__ h_in2,
        __half* __restrict__ h_out,
        const float* __restrict__ W, const float* __restrict__ bias,
        const int* __restrict__ colptr, const int2* __restrict__ csrRW,
        const float* __restrict__ rcnt, int N) {
    __shared__ float sm[4][72];        // 4 waves x 64 floats (+pad)
    int lane = threadIdx.x & 63;
    int warp = threadIdx.x >> 6;
    int grp  = lane >> 4;
    int sub  = lane & 15;
    int wid  = (blockIdx.x * blockDim.x + threadIdx.x) >> 6;
    int nw   = (gridDim.x * blockDim.x) >> 6;
    float* smw = &sm[warp][0];

    float Wc[L];                       // column `lane` of W
    #pragma unroll
    for (int f = 0; f < L; ++f) Wc[f] = W[f * L + lane];
    float bl = bias[lane];

    for (int n = wid; n < N; n += nw) {
        int beg = colptr[n], end = colptr[n + 1];
        float4 sA = make_float4(0.f, 0.f, 0.f, 0.f);
        float4 sB = make_float4(0.f, 0.f, 0.f, 0.f);
        float4 sC = make_float4(0.f, 0.f, 0.f, 0.f);
        float4 sD = make_float4(0.f, 0.f, 0.f, 0.f);
        for (int base = beg; base < end; base += 64) {
            int m = end - base; if (m > 64) m = 64;
            int rm = 0, wb = 0;
            if (lane < m) { int2 md = csrRW[base + lane]; rm = md.x; wb = md.y; }
            int kmax = (m + 3) >> 2;
            int k = 0;
            for (; k + 4 <= kmax; k += 4) {
                int j0 = 4 * k + grp;
                int   r0 = __shfl(rm, j0),      r1 = __shfl(rm, j0 + 4);
                int   r2 = __shfl(rm, j0 + 8),  r3 = __shfl(rm, j0 + 12);
                float w0 = __int_as_float(__shfl(wb, j0));
                float w1 = __int_as_float(__shfl(wb, j0 + 4));
                float w2 = __int_as_float(__shfl(wb, j0 + 8));
                float w3 = __int_as_float(__shfl(wb, j0 + 12));
                uint2 q0 = h_in2[(size_t)r0 * 16 + sub];
                uint2 q1 = h_in2[(size_t)r1 * 16 + sub];
                uint2 q2 = h_in2[(size_t)r2 * 16 + sub];
                uint2 q3 = h_in2[(size_t)r3 * 16 + sub];
                float2 l0 = __half22float2(*(__half2*)&q0.x), g0 = __half22float2(*(__half2*)&q0.y);
                float2 l1 = __half22float2(*(__half2*)&q1.x), g1 = __half22float2(*(__half2*)&q1.y);
                float2 l2 = __half22float2(*(__half2*)&q2.x), g2 = __half22float2(*(__half2*)&q2.y);
                float2 l3 = __half22float2(*(__half2*)&q3.x), g3 = __half22float2(*(__half2*)&q3.y);
                sA.x += w0 * l0.x; sA.y += w0 * l0.y; sA.z += w0 * g0.x; sA.w += w0 * g0.y;
                sB.x += w1 * l1.x; sB.y += w1 * l1.y; sB.z += w1 * g1.x; sB.w += w1 * g1.y;
                sC.x += w2 * l2.x; sC.y += w2 * l2.y; sC.z += w2 * g2.x; sC.w += w2 * g2.y;
                sD.x += w3 * l3.x; sD.y += w3 * l3.y; sD.z += w3 * g3.x; sD.w += w3 * g3.y;
            }
            for (; k < kmax; ++k) {
                int j0 = 4 * k + grp;
                int   r0 = __shfl(rm, j0);
                float w0 = __int_as_float(__shfl(wb, j0));
                uint2 q0 = h_in2[(size_t)r0 * 16 + sub];
                float2 l0 = __half22float2(*(__half2*)&q0.x), g0 = __half22float2(*(__half2*)&q0.y);
                sA.x += w0 * l0.x; sA.y += w0 * l0.y; sA.z += w0 * g0.x; sA.w += w0 * g0.y;
            }
        }
        float4 s;
        s.x = (sA.x + sB.x) + (sC.x + sD.x);
        s.y = (sA.y + sB.y) + (sC.y + sD.y);
        s.z = (sA.z + sB.z) + (sC.z + sD.z);
        s.w = (sA.w + sB.w) + (sC.w + sD.w);
        // combine the 4 edge-groups
        s.x += __shfl_xor(s.x, 16); s.x += __shfl_xor(s.x, 32);
        s.y += __shfl_xor(s.y, 16); s.y += __shfl_xor(s.y, 32);
        s.z += __shfl_xor(s.z, 16); s.z += __shfl_xor(s.z, 32);
        s.w += __shfl_xor(s.w, 16); s.w += __shfl_xor(s.w, 32);
        // stage s (features 4*sub..4*sub+3 live at lane sub) into LDS
        if (grp == 0) {
            smw[4 * sub + 0] = s.x; smw[4 * sub + 1] = s.y;
            smw[4 * sub + 2] = s.z; smw[4 * sub + 3] = s.w;
        }
        __builtin_amdgcn_s_waitcnt(WAITCNT_LGKM0);  // wave-internal LDS RAW fence
        // matvec via uniform-address (broadcast) b128 reads
        float a0 = 0.f, a1 = 0.f, a2 = 0.f, a3 = 0.f;
        const float4* smv = (const float4*)smw;
        #pragma unroll
        for (int q = 0; q < 16; ++q) {
            float4 sv = smv[q];
            a0 += sv.x * Wc[4 * q + 0];
            a1 += sv.y * Wc[4 * q + 1];
            a2 += sv.z * Wc[4 * q + 2];
            a3 += sv.w * Wc[4 * q + 3];
        }
        float o = ((a0 + a1) + (a2 + a3)) * rcnt[n] + bl;
        h_out[(size_t)n * L + lane] = __float2half(fmaxf(o, 0.f));
    }
}

// ---------- fused decoder node matvecs: U = h@W1[:64]+b1, V = h@W1[64:] ----------

__global__ __launch_bounds__(256) void k_mv2(const __half* __restrict__ h,
        const float* __restrict__ W1, const float* __restrict__ b1,
        float* __restrict__ U, float* __restrict__ V, int N) {
    __shared__ float sm[4][72];
    int lane = threadIdx.x & 63;
    int warp = threadIdx.x >> 6;
    int wid  = (blockIdx.x * blockDim.x + threadIdx.x) >> 6;
    int nw   = (gridDim.x * blockDim.x) >> 6;
    float* smw = &sm[warp][0];
    float Wu[L], Wv[L];
    #pragma unroll
    for (int f = 0; f < L; ++f) Wu[f] = W1[f * L + lane];
    #pragma unroll
    for (int f = 0; f < L; ++f) Wv[f] = W1[(L + f) * L + lane];
    float bl = b1[lane];
    for (int n = wid; n < N; n += nw) {
        float hl = __half2float(h[(size_t)n * L + lane]);
        smw[lane] = hl;
        __builtin_amdgcn_s_waitcnt(WAITCNT_LGKM0);
        float a0 = 0.f, a1 = 0.f, c0 = 0.f, c1 = 0.f;
        const float4* smv = (const float4*)smw;
        #pragma unroll
        for (int q = 0; q < 16; ++q) {
            float4 sv = smv[q];
            a0 += sv.x * Wu[4 * q + 0] ; a1 += sv.y * Wu[4 * q + 1];
            a0 += sv.z * Wu[4 * q + 2] ; a1 += sv.w * Wu[4 * q + 3];
            c0 += sv.x * Wv[4 * q + 0] ; c1 += sv.y * Wv[4 * q + 1];
            c0 += sv.z * Wv[4 * q + 2] ; c1 += sv.w * Wv[4 * q + 3];
        }
        U[(size_t)n * L + lane] = (a0 + a1) + bl;
        V[(size_t)n * L + lane] = (c0 + c1);
        __builtin_amdgcn_s_waitcnt(WAITCNT_LGKM0);  // WAR guard before next store
    }
}

// ---------- decoder edge pass, CSR order: V[col] in registers, gather U[row] ----------

__global__ __launch_bounds__(256) void k_edge(const float4* __restrict__ U4,
        const float4* __restrict__ V4, const float* __restrict__ w2,
        const float* __restrict__ b2,
        const int* __restrict__ colptr, const int2* __restrict__ csrRW,
        const int* __restrict__ csrE, float* __restrict__ out, int N) {
    int lane = threadIdx.x & 63;
    int grp  = lane >> 4;
    int sub  = lane & 15;
    int wid  = (blockIdx.x * blockDim.x + threadIdx.x) >> 6;
    int nw   = (gridDim.x * blockDim.x) >> 6;
    float4 w2v = ((const float4*)w2)[sub];
    float b2v = b2[0];

    for (int n = wid; n < N; n += nw) {
        int beg = colptr[n], end = colptr[n + 1];
        float4 v = V4[(size_t)n * 16 + sub];
        for (int base = beg; base < end; base += 64) {
            int m = end - base; if (m > 64) m = 64;
            int rm = 0, em = -1;
            if (lane < m) { rm = csrRW[base + lane].x; em = csrE[base + lane]; }
            int kmax = (m + 3) >> 2;
            int k = 0;
            for (; k + 2 <= kmax; k += 2) {
                int j0 = 4 * k + grp, j1 = j0 + 4;
                int r0 = __shfl(rm, j0), e0 = __shfl(em, j0);
                int r1 = __shfl(rm, j1), e1 = __shfl(em, j1);
                float4 u0 = U4[(size_t)r0 * 16 + sub];
                float4 u1 = U4[(size_t)r1 * 16 + sub];
                float p0 = fmaxf(u0.x + v.x, 0.f) * w2v.x + fmaxf(u0.y + v.y, 0.f) * w2v.y
                         + fmaxf(u0.z + v.z, 0.f) * w2v.z + fmaxf(u0.w + v.w, 0.f) * w2v.w;
                float p1 = fmaxf(u1.x + v.x, 0.f) * w2v.x + fmaxf(u1.y + v.y, 0.f) * w2v.y
                         + fmaxf(u1.z + v.z, 0.f) * w2v.z + fmaxf(u1.w + v.w, 0.f) * w2v.w;
                p0 += __shfl_xor(p0, 8); p0 += __shfl_xor(p0, 4);
                p0 += __shfl_xor(p0, 2); p0 += __shfl_xor(p0, 1);
                p1 += __shfl_xor(p1, 8); p1 += __shfl_xor(p1, 4);
                p1 += __shfl_xor(p1, 2); p1 += __shfl_xor(p1, 1);
                if (sub == 0 && e0 >= 0) {
                    float val = p0 + b2v;
                    if (r0 == n) val = fmaxf(val, 0.f) + log1pf(expf(-fabsf(val)));
                    out[e0] = val;
                }
                if (sub == 0 && e1 >= 0) {
                    float val = p1 + b2v;
                    if (r1 == n) val = fmaxf(val, 0.f) + log1pf(expf(-fabsf(val)));
                    out[e1] = val;
                }
            }
            if (k < kmax) {
                int j0 = 4 * k + grp;
                int r0 = __shfl(rm, j0), e0 = __shfl(em, j0);
                float4 u0 = U4[(size_t)r0 * 16 + sub];
                float p0 = fmaxf(u0.x + v.x, 0.f) * w2v.x + fmaxf(u0.y + v.y, 0.f) * w2v.y
                         + fmaxf(u0.z + v.z, 0.f) * w2v.z + fmaxf(u0.w + v.w, 0.f) * w2v.w;
                p0 += __shfl_xor(p0, 8); p0 += __shfl_xor(p0, 4);
                p0 += __shfl_xor(p0, 2); p0 += __shfl_xor(p0, 1);
                if (sub == 0 && e0 >= 0) {
                    float val = p0 + b2v;
                    if (r0 == n) val = fmaxf(val, 0.f) + log1pf(expf(-fabsf(val)));
                    out[e0] = val;
                }
            }
        }
    }
}

// ---------- launch ----------

extern "C" void kernel_launch(void* const* d_in, const int* in_sizes, int n_in,
                              void* d_out, int out_size, void* d_ws, size_t ws_size,
                              hipStream_t stream) {
    const float* x     = (const float*)d_in[0];
    const float* attr  = (const float*)d_in[1];
    const float* w_enc = (const float*)d_in[2];
    const float* b_enc = (const float*)d_in[3];
    const float* c1w   = (const float*)d_in[4];
    const float* c1b   = (const float*)d_in[5];
    const float* c2w   = (const float*)d_in[6];
    const float* c2b   = (const float*)d_in[7];
    const float* dw1   = (const float*)d_in[8];
    const float* db1   = (const float*)d_in[9];
    const float* dw2   = (const float*)d_in[10];
    const float* db2   = (const float*)d_in[11];
    const int*   erow  = (const int*)d_in[12];
    const int*   ecol  = (const int*)d_in[13];
    int N = in_sizes[0];
    int E = in_sizes[1];
    float* out = (float*)d_out;
    int NBUK = (N + 127) >> 7;

    char* w = (char*)d_ws;
    auto alloc = [&](size_t bytes) {
        char* p = w; w += (bytes + 255) & ~(size_t)255; return p;
    };
    unsigned long long* degcnt = (unsigned long long*)alloc((size_t)N * 8);  // zeroed
    int*   bukCur = (int*)  alloc((size_t)NBUK * 4);                         // zeroed
    size_t zbytes = (size_t)(w - (char*)d_ws);
    float* dinv   = (float*)alloc((size_t)N * 4);
    int*   cntI   = (int*)  alloc((size_t)N * 4);
    float* rcnt   = (float*)alloc((size_t)N * 4);
    int*   colptr = (int*)  alloc((size_t)(N + 1) * 4);
    int*   bsums  = (int*)  alloc(((size_t)(N + 1023) / 1024 + 1) * 4);
    int2*  csrRW  = (int2*) alloc((size_t)E * 8);
    int*   csrE   = (int*)  alloc((size_t)E * 4);
    __half* hA    = (__half*)alloc((size_t)N * L * 2);   // fp16 h ping
    __half* hB    = (__half*)alloc((size_t)N * L * 2);   // fp16 h pong
    float* hU     = (float*)alloc((size_t)N * L * 4);    // decoder U (fp32)
    float* hV     = (float*)alloc((size_t)N * L * 4);    // decoder V (fp32)
    // rec aliases hU: rec consumed (k_binC) long before k_mv2 writes hU,
    // stream order serializes. E*16 = 25.6MB == N*L*4.
    int4*  rec    = (int4*)hU;
    (void)ws_size; (void)n_in; (void)out_size;

    hipMemsetAsync(d_ws, 0, zbytes, stream);

    int eb = (E + 255) / 256;
    int nb = (N + 255) / 256;
    int B  = (N + 1023) / 1024;     // scan chunks
    k_hist<<<eb, 256, 0, stream>>>(ecol, attr, degcnt, E);
    k_dinv<<<nb, 256, 0, stream>>>(degcnt, dinv, cntI, rcnt, N);
    k_scan_a<<<B, 256, 0, stream>>>(cntI, bsums, N);
    k_scan_b<<<1, 1024, 0, stream>>>(bsums, B, colptr, N);
    k_scan_c<<<B, 256, 0, stream>>>(cntI, bsums, colptr, N);
    k_binB<<<eb, 256, 0, stream>>>(erow, ecol, attr, dinv, colptr, bukCur, rec, E);
    k_binC<<<NBUK, 256, 0, stream>>>(rec, colptr, csrRW, csrE, N);
    k_encode<<<(N * L + 255) / 256, 256, 0, stream>>>(x, w_enc, b_enc, hA, N);

    __half* hin = hA; __half* hout = hB;
    for (int i = 0; i < 3; ++i) {
        k_gcn<<<2048, 256, 0, stream>>>((const uint2*)hin, hout, c1w + i * L * L,
                                        c1b + i * L, colptr, csrRW, rcnt, N);
        __half* t = hin; hin = hout; hout = t;
        k_gcn<<<2048, 256, 0, stream>>>((const uint2*)hin, hout, c2w + i * L * L,
                                        c2b + i * L, colptr, csrRW, rcnt, N);
        t = hin; hin = hout; hout = t;
    }
    // final h in hA (fp16). U -> hU (with b1 folded), V -> hV
    k_mv2<<<2048, 256, 0, stream>>>(hin, dw1, db1, hU, hV, N);
    k_edge<<<2048, 256, 0, stream>>>((const float4*)hU, (const float4*)hV,
                                     dw2, db2, colptr, csrRW, csrE, out, N);
}

// Round 8
// 732.403 us; speedup vs baseline: 1.7044x; 1.7044x over previous
//
#include <hip/hip_runtime.h>
#include <hip/hip_bf16.h>
#include <hip/hip_fp16.h>
#include <math.h>

#define L 64
#define FIXS 1048576.0f   // 2^20 fixed-point scale for attr histogram
#define WAITCNT_LGKM0 0xC07F   // vmcnt=63, expcnt=7, lgkmcnt=0

// ---------- preprocessing ----------

// one fire-and-forget 64-bit atomic per edge: (cnt<<32) | fixedpoint(attr)
__global__ void k_hist(const int* __restrict__ col, const float* __restrict__ attr,
                       unsigned long long* __restrict__ degcnt, int E) {
    int e = blockIdx.x * blockDim.x + threadIdx.x;
    if (e < E) {
        int c = col[e];
        unsigned int fx = (unsigned int)(int)rintf(attr[e] * FIXS);
        atomicAdd(&degcnt[c], (1ULL << 32) | (unsigned long long)fx);
    }
}

__global__ void k_dinv(const unsigned long long* __restrict__ degcnt,
                       float* __restrict__ dinv, int* __restrict__ cntI,
                       float* __restrict__ rcnt, int N) {
    int n = blockIdx.x * blockDim.x + threadIdx.x;
    if (n < N) {
        unsigned long long p = degcnt[n];
        int cnt = (int)(p >> 32);
        float d = (float)(unsigned int)(p & 0xffffffffULL) * (1.0f / FIXS);
        dinv[n] = (d > 0.f) ? (1.0f / sqrtf(fmaxf(d, 1e-30f))) : 0.f;
        cntI[n] = cnt;
        int c = cnt; if (c < 1) c = 1;
        rcnt[n] = 1.0f / (float)c;
    }
}

// ---------- device-wide exclusive scan of cntI -> ptr (3 small kernels) ----------

__global__ __launch_bounds__(256) void k_scan_a(const int* __restrict__ cntI,
                                                int* __restrict__ blockSums, int N) {
    __shared__ int red[4];
    int b = blockIdx.x, t = threadIdx.x;
    int base = b * 1024 + t * 4;
    int s = 0;
    #pragma unroll
    for (int i = 0; i < 4; ++i) { int idx = base + i; if (idx < N) s += cntI[idx]; }
    #pragma unroll
    for (int off = 32; off > 0; off >>= 1) s += __shfl_down(s, off);
    if ((t & 63) == 0) red[t >> 6] = s;
    __syncthreads();
    if (t == 0) blockSums[b] = red[0] + red[1] + red[2] + red[3];
}

__global__ __launch_bounds__(1024) void k_scan_b(int* __restrict__ blockSums, int B,
                                                 int* __restrict__ ptr, int N) {
    __shared__ int sh[1024];
    int t = threadIdx.x;
    sh[t] = (t < B) ? blockSums[t] : 0;
    __syncthreads();
    for (int off = 1; off < 1024; off <<= 1) {
        int v = (t >= off) ? sh[t - off] : 0;
        __syncthreads();
        sh[t] += v;
        __syncthreads();
    }
    if (t < B) blockSums[t] = (t == 0) ? 0 : sh[t - 1];   // exclusive
    if (t == B - 1) ptr[N] = sh[t];                        // total
}

__global__ __launch_bounds__(256) void k_scan_c(const int* __restrict__ cntI,
                                                const int* __restrict__ blockSums,
                                                int* __restrict__ ptr, int N) {
    __shared__ int th[256];
    int b = blockIdx.x, t = threadIdx.x;
    int base = b * 1024 + t * 4;
    int v[4]; int s = 0;
    #pragma unroll
    for (int i = 0; i < 4; ++i) {
        int idx = base + i;
        v[i] = (idx < N) ? cntI[idx] : 0;
        s += v[i];
    }
    th[t] = s;
    __syncthreads();
    for (int off = 1; off < 256; off <<= 1) {
        int x = (t >= off) ? th[t - off] : 0;
        __syncthreads();
        th[t] += x;
        __syncthreads();
    }
    int pre = ((t == 0) ? 0 : th[t - 1]) + blockSums[b];
    #pragma unroll
    for (int i = 0; i < 4; ++i) {
        int idx = base + i;
        if (idx < N) ptr[idx] = pre;
        pre += v[i];
    }
}

// ---------- CSR build: single pass, ONE 16B record per edge ----------
// csrX[pos] = {row, bits(norm), eid, 0} -- single random store dirties 1 line
// (R6's two stores to csrRW+csrE dirtied 2 lines -> 148MB write traffic).
__global__ void k_scatter(const int* __restrict__ row, const int* __restrict__ col,
                          const float* __restrict__ attr, const float* __restrict__ dinv,
                          const int* __restrict__ colptr, int* __restrict__ cursor,
                          int4* __restrict__ csrX, int E) {
    int e = blockIdx.x * blockDim.x + threadIdx.x;
    if (e < E) {
        int r = row[e], c = col[e];
        float nrm = dinv[r] * attr[e] * dinv[c];
        int pos = colptr[c] + atomicAdd(&cursor[c], 1);
        csrX[pos] = make_int4(r, __float_as_int(nrm), e, 0);
    }
}

// ---------- encoder (fp16 h) ----------

__global__ void k_encode(const float* __restrict__ x, const float* __restrict__ w_enc,
                         const float* __restrict__ b_enc, __half* __restrict__ h, int N) {
    int idx = blockIdx.x * blockDim.x + threadIdx.x;
    if (idx < N * L) {
        int n = idx >> 6, f = idx & 63;
        h[idx] = __float2half(x[n] * w_enc[f] + b_enc[f]);
    }
}

// ---------- fused GCN layer (fp16 h storage, fp32 accumulate) ----------

__global__ __launch_bounds__(256) void k_gcn(const uint2* __restrict__ h_in2,
        __half* __restrict__ h_out,
        const float* __restrict__ W, const float* __restrict__ bias,
        const int* __restrict__ colptr, const int4* __restrict__ csrX,
        const float* __restrict__ rcnt, int N) {
    __shared__ float sm[4][72];        // 4 waves x 64 floats (+pad)
    int lane = threadIdx.x & 63;
    int warp = threadIdx.x >> 6;
    int grp  = lane >> 4;
    int sub  = lane & 15;
    int wid  = (blockIdx.x * blockDim.x + threadIdx.x) >> 6;
    int nw   = (gridDim.x * blockDim.x) >> 6;
    float* smw = &sm[warp][0];

    float Wc[L];                       // column `lane` of W
    #pragma unroll
    for (int f = 0; f < L; ++f) Wc[f] = W[f * L + lane];
    float bl = bias[lane];

    for (int n = wid; n < N; n += nw) {
        int beg = colptr[n], end = colptr[n + 1];
        float4 sA = make_float4(0.f, 0.f, 0.f, 0.f);
        float4 sB = make_float4(0.f, 0.f, 0.f, 0.f);
        float4 sC = make_float4(0.f, 0.f, 0.f, 0.f);
        float4 sD = make_float4(0.f, 0.f, 0.f, 0.f);
        for (int base = beg; base < end; base += 64) {
            int m = end - base; if (m > 64) m = 64;
            int rm = 0, wb = 0;
            if (lane < m) { int4 md = csrX[base + lane]; rm = md.x; wb = md.y; }
            int kmax = (m + 3) >> 2;
            int k = 0;
            for (; k + 4 <= kmax; k += 4) {
                int j0 = 4 * k + grp;
                int   r0 = __shfl(rm, j0),      r1 = __shfl(rm, j0 + 4);
                int   r2 = __shfl(rm, j0 + 8),  r3 = __shfl(rm, j0 + 12);
                float w0 = __int_as_float(__shfl(wb, j0));
                float w1 = __int_as_float(__shfl(wb, j0 + 4));
                float w2 = __int_as_float(__shfl(wb, j0 + 8));
                float w3 = __int_as_float(__shfl(wb, j0 + 12));
                uint2 q0 = h_in2[(size_t)r0 * 16 + sub];
                uint2 q1 = h_in2[(size_t)r1 * 16 + sub];
                uint2 q2 = h_in2[(size_t)r2 * 16 + sub];
                uint2 q3 = h_in2[(size_t)r3 * 16 + sub];
                float2 l0 = __half22float2(*(__half2*)&q0.x), g0 = __half22float2(*(__half2*)&q0.y);
                float2 l1 = __half22float2(*(__half2*)&q1.x), g1 = __half22float2(*(__half2*)&q1.y);
                float2 l2 = __half22float2(*(__half2*)&q2.x), g2 = __half22float2(*(__half2*)&q2.y);
                float2 l3 = __half22float2(*(__half2*)&q3.x), g3 = __half22float2(*(__half2*)&q3.y);
                sA.x += w0 * l0.x; sA.y += w0 * l0.y; sA.z += w0 * g0.x; sA.w += w0 * g0.y;
                sB.x += w1 * l1.x; sB.y += w1 * l1.y; sB.z += w1 * g1.x; sB.w += w1 * g1.y;
                sC.x += w2 * l2.x; sC.y += w2 * l2.y; sC.z += w2 * g2.x; sC.w += w2 * g2.y;
                sD.x += w3 * l3.x; sD.y += w3 * l3.y; sD.z += w3 * g3.x; sD.w += w3 * g3.y;
            }
            for (; k < kmax; ++k) {
                int j0 = 4 * k + grp;
                int   r0 = __shfl(rm, j0);
                float w0 = __int_as_float(__shfl(wb, j0));
                uint2 q0 = h_in2[(size_t)r0 * 16 + sub];
                float2 l0 = __half22float2(*(__half2*)&q0.x), g0 = __half22float2(*(__half2*)&q0.y);
                sA.x += w0 * l0.x; sA.y += w0 * l0.y; sA.z += w0 * g0.x; sA.w += w0 * g0.y;
            }
        }
        float4 s;
        s.x = (sA.x + sB.x) + (sC.x + sD.x);
        s.y = (sA.y + sB.y) + (sC.y + sD.y);
        s.z = (sA.z + sB.z) + (sC.z + sD.z);
        s.w = (sA.w + sB.w) + (sC.w + sD.w);
        // combine the 4 edge-groups
        s.x += __shfl_xor(s.x, 16); s.x += __shfl_xor(s.x, 32);
        s.y += __shfl_xor(s.y, 16); s.y += __shfl_xor(s.y, 32);
        s.z += __shfl_xor(s.z, 16); s.z += __shfl_xor(s.z, 32);
        s.w += __shfl_xor(s.w, 16); s.w += __shfl_xor(s.w, 32);
        // stage s (features 4*sub..4*sub+3 live at lane sub) into LDS
        if (grp == 0) {
            smw[4 * sub + 0] = s.x; smw[4 * sub + 1] = s.y;
            smw[4 * sub + 2] = s.z; smw[4 * sub + 3] = s.w;
        }
        __builtin_amdgcn_s_waitcnt(WAITCNT_LGKM0);  // wave-internal LDS RAW fence
        // matvec via uniform-address (broadcast) b128 reads
        float a0 = 0.f, a1 = 0.f, a2 = 0.f, a3 = 0.f;
        const float4* smv = (const float4*)smw;
        #pragma unroll
        for (int q = 0; q < 16; ++q) {
            float4 sv = smv[q];
            a0 += sv.x * Wc[4 * q + 0];
            a1 += sv.y * Wc[4 * q + 1];
            a2 += sv.z * Wc[4 * q + 2];
            a3 += sv.w * Wc[4 * q + 3];
        }
        float o = ((a0 + a1) + (a2 + a3)) * rcnt[n] + bl;
        h_out[(size_t)n * L + lane] = __float2half(fmaxf(o, 0.f));
    }
}

// ---------- fused decoder node matvecs: U = h@W1[:64]+b1, V = h@W1[64:] ----------

__global__ __launch_bounds__(256) void k_mv2(const __half* __restrict__ h,
        const float* __restrict__ W1, const float* __restrict__ b1,
        float* __restrict__ U, float* __restrict__ V, int N) {
    __shared__ float sm[4][72];
    int lane = threadIdx.x & 63;
    int warp = threadIdx.x >> 6;
    int wid  = (blockIdx.x * blockDim.x + threadIdx.x) >> 6;
    int nw   = (gridDim.x * blockDim.x) >> 6;
    float* smw = &sm[warp][0];
    float Wu[L], Wv[L];
    #pragma unroll
    for (int f = 0; f < L; ++f) Wu[f] = W1[f * L + lane];
    #pragma unroll
    for (int f = 0; f < L; ++f) Wv[f] = W1[(L + f) * L + lane];
    float bl = b1[lane];
    for (int n = wid; n < N; n += nw) {
        float hl = __half2float(h[(size_t)n * L + lane]);
        smw[lane] = hl;
        __builtin_amdgcn_s_waitcnt(WAITCNT_LGKM0);
        float a0 = 0.f, a1 = 0.f, c0 = 0.f, c1 = 0.f;
        const float4* smv = (const float4*)smw;
        #pragma unroll
        for (int q = 0; q < 16; ++q) {
            float4 sv = smv[q];
            a0 += sv.x * Wu[4 * q + 0] ; a1 += sv.y * Wu[4 * q + 1];
            a0 += sv.z * Wu[4 * q + 2] ; a1 += sv.w * Wu[4 * q + 3];
            c0 += sv.x * Wv[4 * q + 0] ; c1 += sv.y * Wv[4 * q + 1];
            c0 += sv.z * Wv[4 * q + 2] ; c1 += sv.w * Wv[4 * q + 3];
        }
        U[(size_t)n * L + lane] = (a0 + a1) + bl;
        V[(size_t)n * L + lane] = (c0 + c1);
        __builtin_amdgcn_s_waitcnt(WAITCNT_LGKM0);  // WAR guard before next store
    }
}

// ---------- decoder edge pass, CSR order: V[col] in registers, gather U[row] ----------

__global__ __launch_bounds__(256) void k_edge(const float4* __restrict__ U4,
        const float4* __restrict__ V4, const float* __restrict__ w2,
        const float* __restrict__ b2,
        const int* __restrict__ colptr, const int4* __restrict__ csrX,
        float* __restrict__ out, int N) {
    int lane = threadIdx.x & 63;
    int grp  = lane >> 4;
    int sub  = lane & 15;
    int wid  = (blockIdx.x * blockDim.x + threadIdx.x) >> 6;
    int nw   = (gridDim.x * blockDim.x) >> 6;
    float4 w2v = ((const float4*)w2)[sub];
    float b2v = b2[0];

    for (int n = wid; n < N; n += nw) {
        int beg = colptr[n], end = colptr[n + 1];
        float4 v = V4[(size_t)n * 16 + sub];
        for (int base = beg; base < end; base += 64) {
            int m = end - base; if (m > 64) m = 64;
            int rm = 0, em = -1;
            if (lane < m) { int4 md = csrX[base + lane]; rm = md.x; em = md.z; }
            int kmax = (m + 3) >> 2;
            int k = 0;
            for (; k + 2 <= kmax; k += 2) {
                int j0 = 4 * k + grp, j1 = j0 + 4;
                int r0 = __shfl(rm, j0), e0 = __shfl(em, j0);
                int r1 = __shfl(rm, j1), e1 = __shfl(em, j1);
                float4 u0 = U4[(size_t)r0 * 16 + sub];
                float4 u1 = U4[(size_t)r1 * 16 + sub];
                float p0 = fmaxf(u0.x + v.x, 0.f) * w2v.x + fmaxf(u0.y + v.y, 0.f) * w2v.y
                         + fmaxf(u0.z + v.z, 0.f) * w2v.z + fmaxf(u0.w + v.w, 0.f) * w2v.w;
                float p1 = fmaxf(u1.x + v.x, 0.f) * w2v.x + fmaxf(u1.y + v.y, 0.f) * w2v.y
                         + fmaxf(u1.z + v.z, 0.f) * w2v.z + fmaxf(u1.w + v.w, 0.f) * w2v.w;
                p0 += __shfl_xor(p0, 8); p0 += __shfl_xor(p0, 4);
                p0 += __shfl_xor(p0, 2); p0 += __shfl_xor(p0, 1);
                p1 += __shfl_xor(p1, 8); p1 += __shfl_xor(p1, 4);
                p1 += __shfl_xor(p1, 2); p1 += __shfl_xor(p1, 1);
                if (sub == 0 && e0 >= 0) {
                    float val = p0 + b2v;
                    if (r0 == n) val = fmaxf(val, 0.f) + log1pf(expf(-fabsf(val)));
                    out[e0] = val;
                }
                if (sub == 0 && e1 >= 0) {
                    float val = p1 + b2v;
                    if (r1 == n) val = fmaxf(val, 0.f) + log1pf(expf(-fabsf(val)));
                    out[e1] = val;
                }
            }
            if (k < kmax) {
                int j0 = 4 * k + grp;
                int r0 = __shfl(rm, j0), e0 = __shfl(em, j0);
                float4 u0 = U4[(size_t)r0 * 16 + sub];
                float p0 = fmaxf(u0.x + v.x, 0.f) * w2v.x + fmaxf(u0.y + v.y, 0.f) * w2v.y
                         + fmaxf(u0.z + v.z, 0.f) * w2v.z + fmaxf(u0.w + v.w, 0.f) * w2v.w;
                p0 += __shfl_xor(p0, 8); p0 += __shfl_xor(p0, 4);
                p0 += __shfl_xor(p0, 2); p0 += __shfl_xor(p0, 1);
                if (sub == 0 && e0 >= 0) {
                    float val = p0 + b2v;
                    if (r0 == n) val = fmaxf(val, 0.f) + log1pf(expf(-fabsf(val)));
                    out[e0] = val;
                }
            }
        }
    }
}

// ---------- launch ----------

extern "C" void kernel_launch(void* const* d_in, const int* in_sizes, int n_in,
                              void* d_out, int out_size, void* d_ws, size_t ws_size,
                              hipStream_t stream) {
    const float* x     = (const float*)d_in[0];
    const float* attr  = (const float*)d_in[1];
    const float* w_enc = (const float*)d_in[2];
    const float* b_enc = (const float*)d_in[3];
    const float* c1w   = (const float*)d_in[4];
    const float* c1b   = (const float*)d_in[5];
    const float* c2w   = (const float*)d_in[6];
    const float* c2b   = (const float*)d_in[7];
    const float* dw1   = (const float*)d_in[8];
    const float* db1   = (const float*)d_in[9];
    const float* dw2   = (const float*)d_in[10];
    const float* db2   = (const float*)d_in[11];
    const int*   erow  = (const int*)d_in[12];
    const int*   ecol  = (const int*)d_in[13];
    int N = in_sizes[0];
    int E = in_sizes[1];
    float* out = (float*)d_out;

    char* w = (char*)d_ws;
    auto alloc = [&](size_t bytes) {
        char* p = w; w += (bytes + 255) & ~(size_t)255; return p;
    };
    unsigned long long* degcnt = (unsigned long long*)alloc((size_t)N * 8);  // zeroed
    int*   cursor = (int*)  alloc((size_t)N * 4);                            // zeroed
    size_t zbytes = (size_t)(w - (char*)d_ws);
    float* dinv   = (float*)alloc((size_t)N * 4);
    int*   cntI   = (int*)  alloc((size_t)N * 4);
    float* rcnt   = (float*)alloc((size_t)N * 4);
    int*   colptr = (int*)  alloc((size_t)(N + 1) * 4);
    int*   bsums  = (int*)  alloc(((size_t)(N + 1023) / 1024 + 1) * 4);
    int4*  csrX   = (int4*) alloc((size_t)E * 16);
    __half* hA    = (__half*)alloc((size_t)N * L * 2);   // fp16 h ping
    __half* hB    = (__half*)alloc((size_t)N * L * 2);   // fp16 h pong
    float* hU     = (float*)alloc((size_t)N * L * 4);    // decoder U (fp32)
    float* hV     = (float*)alloc((size_t)N * L * 4);    // decoder V (fp32)
    (void)ws_size; (void)n_in; (void)out_size;

    hipMemsetAsync(d_ws, 0, zbytes, stream);

    int eb = (E + 255) / 256;
    int nb = (N + 255) / 256;
    int B  = (N + 1023) / 1024;     // scan chunks
    k_hist<<<eb, 256, 0, stream>>>(ecol, attr, degcnt, E);
    k_dinv<<<nb, 256, 0, stream>>>(degcnt, dinv, cntI, rcnt, N);
    k_scan_a<<<B, 256, 0, stream>>>(cntI, bsums, N);
    k_scan_b<<<1, 1024, 0, stream>>>(bsums, B, colptr, N);
    k_scan_c<<<B, 256, 0, stream>>>(cntI, bsums, colptr, N);
    k_scatter<<<eb, 256, 0, stream>>>(erow, ecol, attr, dinv, colptr, cursor, csrX, E);
    k_encode<<<(N * L + 255) / 256, 256, 0, stream>>>(x, w_enc, b_enc, hA, N);

    __half* hin = hA; __half* hout = hB;
    for (int i = 0; i < 3; ++i) {
        k_gcn<<<2048, 256, 0, stream>>>((const uint2*)hin, hout, c1w + i * L * L,
                                        c1b + i * L, colptr, csrX, rcnt, N);
        __half* t = hin; hin = hout; hout = t;
        k_gcn<<<2048, 256, 0, stream>>>((const uint2*)hin, hout, c2w + i * L * L,
                                        c2b + i * L, colptr, csrX, rcnt, N);
        t = hin; hin = hout; hout = t;
    }
    // final h in hA (fp16). U -> hU (with b1 folded), V -> hV
    k_mv2<<<2048, 256, 0, stream>>>(hin, dw1, db1, hU, hV, N);
    k_edge<<<2048, 256, 0, stream>>>((const float4*)hU, (const float4*)hV,
                                     dw2, db2, colptr, csrX, out, N);
}

// Round 10
// 715.801 us; speedup vs baseline: 1.7440x; 1.0232x over previous
//
#include <hip/hip_runtime.h>
#include <hip/hip_fp16.h>
#include <math.h>

#define L 64
#define FIXS 1048576.0f   // 2^20 fixed-point scale for attr histogram
#define WAITCNT_LGKM0 0xC07F   // vmcnt=63, expcnt=7, lgkmcnt=0

// packed-half helpers with pinned types (avoids bf16-header overload ambiguity)
static __device__ __forceinline__ __half2 h2add(__half2 a, __half2 b) {
    return __half2{__hadd(a.x, b.x), __hadd(a.y, b.y)};
}
static __device__ __forceinline__ __half2 h2relu(__half2 a) {
    const __half z = __float2half(0.f);
    return __half2{__hgt(a.x, z) ? a.x : z, __hgt(a.y, z) ? a.y : z};
}

// ---------- preprocessing ----------

// one fire-and-forget 64-bit atomic per edge: (cnt<<32) | fixedpoint(attr)
__global__ void k_hist(const int* __restrict__ col, const float* __restrict__ attr,
                       unsigned long long* __restrict__ degcnt, int E) {
    int e = blockIdx.x * blockDim.x + threadIdx.x;
    if (e < E) {
        int c = col[e];
        unsigned int fx = (unsigned int)(int)rintf(attr[e] * FIXS);
        atomicAdd(&degcnt[c], (1ULL << 32) | (unsigned long long)fx);
    }
}

__global__ void k_dinv(const unsigned long long* __restrict__ degcnt,
                       float* __restrict__ dinv, int* __restrict__ cntI,
                       float* __restrict__ rcnt, int N) {
    int n = blockIdx.x * blockDim.x + threadIdx.x;
    if (n < N) {
        unsigned long long p = degcnt[n];
        int cnt = (int)(p >> 32);
        float d = (float)(unsigned int)(p & 0xffffffffULL) * (1.0f / FIXS);
        dinv[n] = (d > 0.f) ? (1.0f / sqrtf(fmaxf(d, 1e-30f))) : 0.f;
        cntI[n] = cnt;
        int c = cnt; if (c < 1) c = 1;
        rcnt[n] = 1.0f / (float)c;
    }
}

// ---------- device-wide exclusive scan of cntI -> ptr (3 small kernels) ----------

__global__ __launch_bounds__(256) void k_scan_a(const int* __restrict__ cntI,
                                                int* __restrict__ blockSums, int N) {
    __shared__ int red[4];
    int b = blockIdx.x, t = threadIdx.x;
    int base = b * 1024 + t * 4;
    int s = 0;
    #pragma unroll
    for (int i = 0; i < 4; ++i) { int idx = base + i; if (idx < N) s += cntI[idx]; }
    #pragma unroll
    for (int off = 32; off > 0; off >>= 1) s += __shfl_down(s, off);
    if ((t & 63) == 0) red[t >> 6] = s;
    __syncthreads();
    if (t == 0) blockSums[b] = red[0] + red[1] + red[2] + red[3];
}

__global__ __launch_bounds__(1024) void k_scan_b(int* __restrict__ blockSums, int B,
                                                 int* __restrict__ ptr, int N) {
    __shared__ int sh[1024];
    int t = threadIdx.x;
    sh[t] = (t < B) ? blockSums[t] : 0;
    __syncthreads();
    for (int off = 1; off < 1024; off <<= 1) {
        int v = (t >= off) ? sh[t - off] : 0;
        __syncthreads();
        sh[t] += v;
        __syncthreads();
    }
    if (t < B) blockSums[t] = (t == 0) ? 0 : sh[t - 1];   // exclusive
    if (t == B - 1) ptr[N] = sh[t];                        // total
}

__global__ __launch_bounds__(256) void k_scan_c(const int* __restrict__ cntI,
                                                const int* __restrict__ blockSums,
                                                int* __restrict__ ptr, int N) {
    __shared__ int th[256];
    int b = blockIdx.x, t = threadIdx.x;
    int base = b * 1024 + t * 4;
    int v[4]; int s = 0;
    #pragma unroll
    for (int i = 0; i < 4; ++i) {
        int idx = base + i;
        v[i] = (idx < N) ? cntI[idx] : 0;
        s += v[i];
    }
    th[t] = s;
    __syncthreads();
    for (int off = 1; off < 256; off <<= 1) {
        int x = (t >= off) ? th[t - off] : 0;
        __syncthreads();
        th[t] += x;
        __syncthreads();
    }
    int pre = ((t == 0) ? 0 : th[t - 1]) + blockSums[b];
    #pragma unroll
    for (int i = 0; i < 4; ++i) {
        int idx = base + i;
        if (idx < N) ptr[idx] = pre;
        pre += v[i];
    }
}

// ---------- CSR build: single pass, ONE 8B record per edge ----------
// record: w0 = row(17b) | eid[14:0]<<17 ; w1 = eid[20:15] | fp16(norm)<<16
__global__ void k_scatter(const int* __restrict__ row, const int* __restrict__ col,
                          const float* __restrict__ attr, const float* __restrict__ dinv,
                          const int* __restrict__ colptr, int* __restrict__ cursor,
                          uint2* __restrict__ csrX, int E) {
    int e = blockIdx.x * blockDim.x + threadIdx.x;
    if (e < E) {
        int r = row[e], c = col[e];
        float nrm = dinv[r] * attr[e] * dinv[c];
        unsigned short nb = __half_as_ushort(__float2half(nrm));
        unsigned int w0 = (unsigned)r | (((unsigned)e & 0x7FFFu) << 17);
        unsigned int w1 = ((unsigned)e >> 15) | ((unsigned)nb << 16);
        int pos = colptr[c] + atomicAdd(&cursor[c], 1);
        csrX[pos] = make_uint2(w0, w1);
    }
}

// ---------- encoder (fp16 h) ----------

__global__ void k_encode(const float* __restrict__ x, const float* __restrict__ w_enc,
                         const float* __restrict__ b_enc, __half* __restrict__ h, int N) {
    int idx = blockIdx.x * blockDim.x + threadIdx.x;
    if (idx < N * L) {
        int n = idx >> 6, f = idx & 63;
        h[idx] = __float2half(x[n] * w_enc[f] + b_enc[f]);
    }
}

// ---------- fused GCN layer (fp16 h storage, fp32 accumulate) ----------

__global__ __launch_bounds__(256) void k_gcn(const uint2* __restrict__ h_in2,
        __half* __restrict__ h_out,
        const float* __restrict__ W, const float* __restrict__ bias,
        const int* __restrict__ colptr, const uint2* __restrict__ csrX,
        const float* __restrict__ rcnt, int N) {
    __shared__ float sm[4][72];        // 4 waves x 64 floats (+pad)
    int lane = threadIdx.x & 63;
    int warp = threadIdx.x >> 6;
    int grp  = lane >> 4;
    int sub  = lane & 15;
    int wid  = (blockIdx.x * blockDim.x + threadIdx.x) >> 6;
    int nw   = (gridDim.x * blockDim.x) >> 6;
    float* smw = &sm[warp][0];

    float Wc[L];                       // column `lane` of W
    #pragma unroll
    for (int f = 0; f < L; ++f) Wc[f] = W[f * L + lane];
    float bl = bias[lane];

    for (int n = wid; n < N; n += nw) {
        int beg = colptr[n], end = colptr[n + 1];
        float4 sA = make_float4(0.f, 0.f, 0.f, 0.f);
        float4 sB = make_float4(0.f, 0.f, 0.f, 0.f);
        float4 sC = make_float4(0.f, 0.f, 0.f, 0.f);
        float4 sD = make_float4(0.f, 0.f, 0.f, 0.f);
        for (int base = beg; base < end; base += 64) {
            int m = end - base; if (m > 64) m = 64;
            int rm = 0, wb = 0;
            if (lane < m) {
                uint2 md = csrX[base + lane];
                rm = (int)(md.x & 0x1FFFFu);   // row
                wb = __float_as_int(__half2float(__ushort_as_half((unsigned short)(md.y >> 16))));
            }
            int kmax = (m + 3) >> 2;
            int k = 0;
            for (; k + 4 <= kmax; k += 4) {
                int j0 = 4 * k + grp;
                int   r0 = __shfl(rm, j0),      r1 = __shfl(rm, j0 + 4);
                int   r2 = __shfl(rm, j0 + 8),  r3 = __shfl(rm, j0 + 12);
                float w0 = __int_as_float(__shfl(wb, j0));
                float w1 = __int_as_float(__shfl(wb, j0 + 4));
                float w2 = __int_as_float(__shfl(wb, j0 + 8));
                float w3 = __int_as_float(__shfl(wb, j0 + 12));
                uint2 q0 = h_in2[(size_t)r0 * 16 + sub];
                uint2 q1 = h_in2[(size_t)r1 * 16 + sub];
                uint2 q2 = h_in2[(size_t)r2 * 16 + sub];
                uint2 q3 = h_in2[(size_t)r3 * 16 + sub];
                float2 l0 = __half22float2(*(__half2*)&q0.x), g0 = __half22float2(*(__half2*)&q0.y);
                float2 l1 = __half22float2(*(__half2*)&q1.x), g1 = __half22float2(*(__half2*)&q1.y);
                float2 l2 = __half22float2(*(__half2*)&q2.x), g2 = __half22float2(*(__half2*)&q2.y);
                float2 l3 = __half22float2(*(__half2*)&q3.x), g3 = __half22float2(*(__half2*)&q3.y);
                sA.x += w0 * l0.x; sA.y += w0 * l0.y; sA.z += w0 * g0.x; sA.w += w0 * g0.y;
                sB.x += w1 * l1.x; sB.y += w1 * l1.y; sB.z += w1 * g1.x; sB.w += w1 * g1.y;
                sC.x += w2 * l2.x; sC.y += w2 * l2.y; sC.z += w2 * g2.x; sC.w += w2 * g2.y;
                sD.x += w3 * l3.x; sD.y += w3 * l3.y; sD.z += w3 * g3.x; sD.w += w3 * g3.y;
            }
            for (; k < kmax; ++k) {
                int j0 = 4 * k + grp;
                int   r0 = __shfl(rm, j0);
                float w0 = __int_as_float(__shfl(wb, j0));
                uint2 q0 = h_in2[(size_t)r0 * 16 + sub];
                float2 l0 = __half22float2(*(__half2*)&q0.x), g0 = __half22float2(*(__half2*)&q0.y);
                sA.x += w0 * l0.x; sA.y += w0 * l0.y; sA.z += w0 * g0.x; sA.w += w0 * g0.y;
            }
        }
        float4 s;
        s.x = (sA.x + sB.x) + (sC.x + sD.x);
        s.y = (sA.y + sB.y) + (sC.y + sD.y);
        s.z = (sA.z + sB.z) + (sC.z + sD.z);
        s.w = (sA.w + sB.w) + (sC.w + sD.w);
        // combine the 4 edge-groups
        s.x += __shfl_xor(s.x, 16); s.x += __shfl_xor(s.x, 32);
        s.y += __shfl_xor(s.y, 16); s.y += __shfl_xor(s.y, 32);
        s.z += __shfl_xor(s.z, 16); s.z += __shfl_xor(s.z, 32);
        s.w += __shfl_xor(s.w, 16); s.w += __shfl_xor(s.w, 32);
        // stage s (features 4*sub..4*sub+3 live at lane sub) into LDS
        if (grp == 0) {
            smw[4 * sub + 0] = s.x; smw[4 * sub + 1] = s.y;
            smw[4 * sub + 2] = s.z; smw[4 * sub + 3] = s.w;
        }
        __builtin_amdgcn_s_waitcnt(WAITCNT_LGKM0);  // wave-internal LDS RAW fence
        // matvec via uniform-address (broadcast) b128 reads
        float a0 = 0.f, a1 = 0.f, a2 = 0.f, a3 = 0.f;
        const float4* smv = (const float4*)smw;
        #pragma unroll
        for (int q = 0; q < 16; ++q) {
            float4 sv = smv[q];
            a0 += sv.x * Wc[4 * q + 0];
            a1 += sv.y * Wc[4 * q + 1];
            a2 += sv.z * Wc[4 * q + 2];
            a3 += sv.w * Wc[4 * q + 3];
        }
        float o = ((a0 + a1) + (a2 + a3)) * rcnt[n] + bl;
        h_out[(size_t)n * L + lane] = __float2half(fmaxf(o, 0.f));
    }
}

// ---------- fused decoder node matvecs: U = h@W1[:64]+b1, V = h@W1[64:] (fp16 out) ----------

__global__ __launch_bounds__(256) void k_mv2(const __half* __restrict__ h,
        const float* __restrict__ W1, const float* __restrict__ b1,
        __half* __restrict__ U, __half* __restrict__ V, int N) {
    __shared__ float sm[4][72];
    int lane = threadIdx.x & 63;
    int warp = threadIdx.x >> 6;
    int wid  = (blockIdx.x * blockDim.x + threadIdx.x) >> 6;
    int nw   = (gridDim.x * blockDim.x) >> 6;
    float* smw = &sm[warp][0];
    float Wu[L], Wv[L];
    #pragma unroll
    for (int f = 0; f < L; ++f) Wu[f] = W1[f * L + lane];
    #pragma unroll
    for (int f = 0; f < L; ++f) Wv[f] = W1[(L + f) * L + lane];
    float bl = b1[lane];
    for (int n = wid; n < N; n += nw) {
        float hl = __half2float(h[(size_t)n * L + lane]);
        smw[lane] = hl;
        __builtin_amdgcn_s_waitcnt(WAITCNT_LGKM0);
        float a0 = 0.f, a1 = 0.f, c0 = 0.f, c1 = 0.f;
        const float4* smv = (const float4*)smw;
        #pragma unroll
        for (int q = 0; q < 16; ++q) {
            float4 sv = smv[q];
            a0 += sv.x * Wu[4 * q + 0] ; a1 += sv.y * Wu[4 * q + 1];
            a0 += sv.z * Wu[4 * q + 2] ; a1 += sv.w * Wu[4 * q + 3];
            c0 += sv.x * Wv[4 * q + 0] ; c1 += sv.y * Wv[4 * q + 1];
            c0 += sv.z * Wv[4 * q + 2] ; c1 += sv.w * Wv[4 * q + 3];
        }
        U[(size_t)n * L + lane] = __float2half((a0 + a1) + bl);
        V[(size_t)n * L + lane] = __float2half(c0 + c1);
        __builtin_amdgcn_s_waitcnt(WAITCNT_LGKM0);  // WAR guard before next store
    }
}

// ---------- decoder edge pass, CSR order: fp16 V[col] in regs, gather fp16 U[row] ----------

__global__ __launch_bounds__(256) void k_edge(const uint2* __restrict__ U2,
        const uint2* __restrict__ V2, const float* __restrict__ w2,
        const float* __restrict__ b2,
        const int* __restrict__ colptr, const uint2* __restrict__ csrX,
        float* __restrict__ out, int N) {
    int lane = threadIdx.x & 63;
    int grp  = lane >> 4;
    int sub  = lane & 15;
    int wid  = (blockIdx.x * blockDim.x + threadIdx.x) >> 6;
    int nw   = (gridDim.x * blockDim.x) >> 6;
    float4 w2v = ((const float4*)w2)[sub];
    float b2v = b2[0];

    for (int n = wid; n < N; n += nw) {
        int beg = colptr[n], end = colptr[n + 1];
        uint2 qv = V2[(size_t)n * 16 + sub];
        __half2 va = *(__half2*)&qv.x, vb = *(__half2*)&qv.y;
        for (int base = beg; base < end; base += 64) {
            int m = end - base; if (m > 64) m = 64;
            int rm = 0, em = -1;
            if (lane < m) {
                uint2 md = csrX[base + lane];
                rm = (int)(md.x & 0x1FFFFu);
                em = (int)((md.x >> 17) | ((md.y & 0x3Fu) << 15));
            }
            int kmax = (m + 3) >> 2;
            int k = 0;
            for (; k + 2 <= kmax; k += 2) {
                int j0 = 4 * k + grp, j1 = j0 + 4;
                int r0 = __shfl(rm, j0), e0 = __shfl(em, j0);
                int r1 = __shfl(rm, j1), e1 = __shfl(em, j1);
                uint2 q0 = U2[(size_t)r0 * 16 + sub];
                uint2 q1 = U2[(size_t)r1 * 16 + sub];
                __half2 t0a = h2relu(h2add(*(__half2*)&q0.x, va));
                __half2 t0b = h2relu(h2add(*(__half2*)&q0.y, vb));
                __half2 t1a = h2relu(h2add(*(__half2*)&q1.x, va));
                __half2 t1b = h2relu(h2add(*(__half2*)&q1.y, vb));
                float2 f0a = __half22float2(t0a), f0b = __half22float2(t0b);
                float2 f1a = __half22float2(t1a), f1b = __half22float2(t1b);
                float p0 = f0a.x * w2v.x + f0a.y * w2v.y + f0b.x * w2v.z + f0b.y * w2v.w;
                float p1 = f1a.x * w2v.x + f1a.y * w2v.y + f1b.x * w2v.z + f1b.y * w2v.w;
                p0 += __shfl_xor(p0, 8); p0 += __shfl_xor(p0, 4);
                p0 += __shfl_xor(p0, 2); p0 += __shfl_xor(p0, 1);
                p1 += __shfl_xor(p1, 8); p1 += __shfl_xor(p1, 4);
                p1 += __shfl_xor(p1, 2); p1 += __shfl_xor(p1, 1);
                if (sub == 0 && e0 >= 0) {
                    float val = p0 + b2v;
                    if (r0 == n) val = fmaxf(val, 0.f) + log1pf(expf(-fabsf(val)));
                    out[e0] = val;
                }
                if (sub == 0 && e1 >= 0) {
                    float val = p1 + b2v;
                    if (r1 == n) val = fmaxf(val, 0.f) + log1pf(expf(-fabsf(val)));
                    out[e1] = val;
                }
            }
            if (k < kmax) {
                int j0 = 4 * k + grp;
                int r0 = __shfl(rm, j0), e0 = __shfl(em, j0);
                uint2 q0 = U2[(size_t)r0 * 16 + sub];
                __half2 t0a = h2relu(h2add(*(__half2*)&q0.x, va));
                __half2 t0b = h2relu(h2add(*(__half2*)&q0.y, vb));
                float2 f0a = __half22float2(t0a), f0b = __half22float2(t0b);
                float p0 = f0a.x * w2v.x + f0a.y * w2v.y + f0b.x * w2v.z + f0b.y * w2v.w;
                p0 += __shfl_xor(p0, 8); p0 += __shfl_xor(p0, 4);
                p0 += __shfl_xor(p0, 2); p0 += __shfl_xor(p0, 1);
                if (sub == 0 && e0 >= 0) {
                    float val = p0 + b2v;
                    if (r0 == n) val = fmaxf(val, 0.f) + log1pf(expf(-fabsf(val)));
                    out[e0] = val;
                }
            }
        }
    }
}

// ---------- launch ----------

extern "C" void kernel_launch(void* const* d_in, const int* in_sizes, int n_in,
                              void* d_out, int out_size, void* d_ws, size_t ws_size,
                              hipStream_t stream) {
    const float* x     = (const float*)d_in[0];
    const float* attr  = (const float*)d_in[1];
    const float* w_enc = (const float*)d_in[2];
    const float* b_enc = (const float*)d_in[3];
    const float* c1w   = (const float*)d_in[4];
    const float* c1b   = (const float*)d_in[5];
    const float* c2w   = (const float*)d_in[6];
    const float* c2b   = (const float*)d_in[7];
    const float* dw1   = (const float*)d_in[8];
    const float* db1   = (const float*)d_in[9];
    const float* dw2   = (const float*)d_in[10];
    const float* db2   = (const float*)d_in[11];
    const int*   erow  = (const int*)d_in[12];
    const int*   ecol  = (const int*)d_in[13];
    int N = in_sizes[0];
    int E = in_sizes[1];
    float* out = (float*)d_out;

    char* w = (char*)d_ws;
    auto alloc = [&](size_t bytes) {
        char* p = w; w += (bytes + 255) & ~(size_t)255; return p;
    };
    unsigned long long* degcnt = (unsigned long long*)alloc((size_t)N * 8);  // zeroed
    int*   cursor = (int*)  alloc((size_t)N * 4);                            // zeroed
    size_t zbytes = (size_t)(w - (char*)d_ws);
    float* dinv   = (float*)alloc((size_t)N * 4);
    int*   cntI   = (int*)  alloc((size_t)N * 4);
    float* rcnt   = (float*)alloc((size_t)N * 4);
    int*   colptr = (int*)  alloc((size_t)(N + 1) * 4);
    int*   bsums  = (int*)  alloc(((size_t)(N + 1023) / 1024 + 1) * 4);
    uint2* csrX   = (uint2*)alloc((size_t)E * 8);
    __half* hA    = (__half*)alloc((size_t)N * L * 2);   // fp16 h ping
    __half* hB    = (__half*)alloc((size_t)N * L * 2);   // fp16 h pong
    __half* hU    = (__half*)alloc((size_t)N * L * 2);   // decoder U (fp16)
    __half* hV    = (__half*)alloc((size_t)N * L * 2);   // decoder V (fp16)
    (void)ws_size; (void)n_in; (void)out_size;

    (void)hipMemsetAsync(d_ws, 0, zbytes, stream);

    int eb = (E + 255) / 256;
    int nb = (N + 255) / 256;
    int B  = (N + 1023) / 1024;     // scan chunks
    k_hist<<<eb, 256, 0, stream>>>(ecol, attr, degcnt, E);
    k_dinv<<<nb, 256, 0, stream>>>(degcnt, dinv, cntI, rcnt, N);
    k_scan_a<<<B, 256, 0, stream>>>(cntI, bsums, N);
    k_scan_b<<<1, 1024, 0, stream>>>(bsums, B, colptr, N);
    k_scan_c<<<B, 256, 0, stream>>>(cntI, bsums, colptr, N);
    k_scatter<<<eb, 256, 0, stream>>>(erow, ecol, attr, dinv, colptr, cursor, csrX, E);
    k_encode<<<(N * L + 255) / 256, 256, 0, stream>>>(x, w_enc, b_enc, hA, N);

    __half* hin = hA; __half* hout = hB;
    for (int i = 0; i < 3; ++i) {
        k_gcn<<<2048, 256, 0, stream>>>((const uint2*)hin, hout, c1w + i * L * L,
                                        c1b + i * L, colptr, csrX, rcnt, N);
        __half* t = hin; hin = hout; hout = t;
        k_gcn<<<2048, 256, 0, stream>>>((const uint2*)hin, hout, c2w + i * L * L,
                                        c2b + i * L, colptr, csrX, rcnt, N);
        t = hin; hin = hout; hout = t;
    }
    // final h in hA (fp16). U -> hU (with b1 folded), V -> hV
    k_mv2<<<2048, 256, 0, stream>>>(hin, dw1, db1, hU, hV, N);
    k_edge<<<2048, 256, 0, stream>>>((const uint2*)hU, (const uint2*)hV,
                                     dw2, db2, colptr, csrX, out, N);
}